// Round 6
// baseline (316.332 us; speedup 1.0000x reference)
//
#include <hip/hip_runtime.h>
#include <hip/hip_bf16.h>
#include <math.h>

// Problem constants
#define B_SZ   1024
#define F_SZ   1024
#define NKER   100
#define DKER   5
#define CCOLS  (NKER * DKER)   // 500
#define OUTW   (F_SZ + NKER)   // 1124
#define LOG2E_F 1.44269504088896340736f

typedef __attribute__((ext_vector_type(8))) short bf16x8;
typedef __attribute__((ext_vector_type(4))) float f32x4;
typedef __attribute__((ext_vector_type(4))) short short4v;
typedef __attribute__((ext_vector_type(8))) short short8v;

// f32 -> bf16 round-to-nearest-even (data is well-behaved normals; no NaN path)
__device__ __forceinline__ short f2bf(float f) {
    unsigned int u = __float_as_uint(f);
    u += 0x7FFFu + ((u >> 16) & 1u);
    return (short)(u >> 16);
}

// Guaranteed single-instruction exp2 (hardware v_exp_f32: input must be the
// already-negated exponent). Flush-to-zero for x < -126 is exactly what we
// want (contributions < 2^-126 are negligible).
__device__ __forceinline__ float exp2_hw(float x) {
    float r;
    asm("v_exp_f32 %0, %1" : "=v"(r) : "v"(x));
    return r;
}

// ---------------------------------------------------------------------------
// Kernel 1: copy x into out[:, :1024], zero feat region out[:, 1024:], and
// zero mt (gemm accumulates into it with atomics). Fused to cut a launch.
// ---------------------------------------------------------------------------
__global__ __launch_bounds__(320) void init_kernel(const float* __restrict__ x,
                                                   float* __restrict__ out,
                                                   float* __restrict__ mt) {
    const int row = blockIdx.x;
    const int t = threadIdx.x;
    if (t < 256) {
        const float4 v = *reinterpret_cast<const float4*>(&x[row * F_SZ + t * 4]);
        *reinterpret_cast<float4*>(&out[row * OUTW + t * 4]) = v;
        if (row < CCOLS) {
            reinterpret_cast<float4*>(mt)[row * 256 + t] =
                make_float4(0.f, 0.f, 0.f, 0.f);
        }
    } else if (t < 256 + 25) {
        float4 z = make_float4(0.f, 0.f, 0.f, 0.f);
        *reinterpret_cast<float4*>(&out[row * OUTW + F_SZ + (t - 256) * 4]) = z;
    }
}

// ---------------------------------------------------------------------------
// Kernel 2: bf16 MFMA GEMM, split-K=4, atomicAdd epilogue (scaled by LOG2E):
//   mt[c][j] = LOG2E * sum_f x[j][f] * T[f][c]
// Round-5 version had 256 blocks = 1 block/CU = 1 wave/SIMD -> the 2-barrier
// K-loop was fully latency-serialized (~59us). Split-K=4 gives 1024 blocks =
// 4 blocks/CU = 4 waves/SIMD so other blocks' waves fill each stall.
// mfma_f32_16x16x32_bf16; A/B frag: lane holds 8 contig k at row=l&15,
// kchunk=(l>>4)*8; C/D: col=lane&15, row=(lane>>4)*4+reg (m89-verified).
// ---------------------------------------------------------------------------
#define GBM 32
#define GBN 64
#define GBK 32
#define NSL 4
#define SSTEP (F_SZ / NSL / GBK)   // 8 K-steps per slice
#define APAD 40                    // LDS row: 32 bf16 + 8 pad (80B, 16B-aligned)

__global__ __launch_bounds__(256) void gemm_mfma_splitk(const float* __restrict__ x,
                                                        const float* __restrict__ T,
                                                        float* __restrict__ mt) {
    __shared__ short Al[GBM][APAD];   // [c][k] bf16
    __shared__ short Bl[GBN][APAD];   // [j][k] bf16
    const int tid = threadIdx.x;
    const int l = tid & 63;
    const int w = tid >> 6;            // wave 0..3 -> j sub-tile
    const int c0 = blockIdx.x * GBM;
    const int j0 = blockIdx.y * GBN;
    const int fb = blockIdx.z * (F_SZ / NSL);

    // A staging: thread -> (c-offset, k-base), 4 elems; B: (j-offset, k-base), 8
    const int ac = tid & 31;
    const int arB = (tid >> 5) * 4;
    const bool aval = (c0 + ac) < CCOLS;
    const int bjr = tid >> 2;
    const int bfc = (tid & 3) * 8;

    float aF0, aF1, aF2, aF3;
    float4 bF0, bF1;
    {
        const float* tp = &T[(fb + arB) * CCOLS + c0 + ac];
        aF0 = aval ? tp[0 * CCOLS] : 0.f;
        aF1 = aval ? tp[1 * CCOLS] : 0.f;
        aF2 = aval ? tp[2 * CCOLS] : 0.f;
        aF3 = aval ? tp[3 * CCOLS] : 0.f;
        const float* xp = &x[(j0 + bjr) * F_SZ + fb + bfc];
        bF0 = *reinterpret_cast<const float4*>(xp);
        bF1 = *reinterpret_cast<const float4*>(xp + 4);
    }

    f32x4 acc0 = {0.f, 0.f, 0.f, 0.f};
    f32x4 acc1 = {0.f, 0.f, 0.f, 0.f};

    const int fr = (l >> 4) * 8;
    const int arow0 = (l & 15);
    const int brow = w * 16 + (l & 15);

    for (int s = 0; s < SSTEP; ++s) {
        if (s) __syncthreads();
        {
            short4v aw;
            aw.x = f2bf(aF0); aw.y = f2bf(aF1); aw.z = f2bf(aF2); aw.w = f2bf(aF3);
            *reinterpret_cast<short4v*>(&Al[ac][arB]) = aw;
            short8v bw;
            bw.s0 = f2bf(bF0.x); bw.s1 = f2bf(bF0.y); bw.s2 = f2bf(bF0.z); bw.s3 = f2bf(bF0.w);
            bw.s4 = f2bf(bF1.x); bw.s5 = f2bf(bF1.y); bw.s6 = f2bf(bF1.z); bw.s7 = f2bf(bF1.w);
            *reinterpret_cast<short8v*>(&Bl[bjr][bfc]) = bw;
        }
        __syncthreads();
        if (s + 1 < SSTEP) {
            const int f0 = fb + (s + 1) * GBK;
            const float* tp = &T[(f0 + arB) * CCOLS + c0 + ac];
            aF0 = aval ? tp[0 * CCOLS] : 0.f;
            aF1 = aval ? tp[1 * CCOLS] : 0.f;
            aF2 = aval ? tp[2 * CCOLS] : 0.f;
            aF3 = aval ? tp[3 * CCOLS] : 0.f;
            const float* xp = &x[(j0 + bjr) * F_SZ + f0 + bfc];
            bF0 = *reinterpret_cast<const float4*>(xp);
            bF1 = *reinterpret_cast<const float4*>(xp + 4);
        }
        const bf16x8 bfrag = *reinterpret_cast<const bf16x8*>(&Bl[brow][fr]);
        const bf16x8 af0 = *reinterpret_cast<const bf16x8*>(&Al[arow0][fr]);
        const bf16x8 af1 = *reinterpret_cast<const bf16x8*>(&Al[16 + arow0][fr]);
        acc0 = __builtin_amdgcn_mfma_f32_16x16x32_bf16(af0, bfrag, acc0, 0, 0, 0);
        acc1 = __builtin_amdgcn_mfma_f32_16x16x32_bf16(af1, bfrag, acc1, 0, 0, 0);
    }

    // epilogue: scale by LOG2E, atomically accumulate the K-slice
    const int jst = j0 + w * 16 + (l & 15);
    const int crow = c0 + ((l >> 4) * 4);
    #pragma unroll
    for (int q = 0; q < 4; ++q) {
        const int cA = crow + q;
        if (cA < CCOLS) atomicAdd(&mt[cA * B_SZ + jst], acc0[q] * LOG2E_F);
        const int cB = crow + 16 + q;
        if (cB < CCOLS) atomicAdd(&mt[cB * B_SZ + jst], acc1[q] * LOG2E_F);
    }
}

// ---------------------------------------------------------------------------
// Kernel 3: pairwise exp-L1. IPT=4 i per thread. JCHUNK=32 -> grid (32,100) =
// 3200 blocks = 12.5/CU: tail imbalance 28%->4% and ~2x occupancy (round-5:
// 800 blocks, 107 cy/wave-pair vs ~30 ideal). exp is one v_exp_f32 via asm
// (library exp2f was multi-inst). mt is pre-scaled by LOG2E in the gemm.
// ---------------------------------------------------------------------------
#define JCHUNK 32
#define JSPLIT (B_SZ / JCHUNK)   // 32

__global__ __launch_bounds__(256) void pair_kernel(const float* __restrict__ mt,
                                                   float* __restrict__ out) {
    __shared__ float mj[DKER][JCHUNK];
    const int tid = threadIdx.x;
    const int j0 = blockIdx.x * JCHUNK;
    const int k = blockIdx.y;
    const int cb = k * DKER;

    if (tid < DKER * JCHUNK) {
        const int d = tid >> 5;
        const int jr = tid & (JCHUNK - 1);
        mj[d][jr] = mt[(cb + d) * B_SZ + j0 + jr];
    }

    const float* r0 = &mt[(cb + 0) * B_SZ];
    const float* r1 = &mt[(cb + 1) * B_SZ];
    const float* r2 = &mt[(cb + 2) * B_SZ];
    const float* r3 = &mt[(cb + 3) * B_SZ];
    const float* r4 = &mt[(cb + 4) * B_SZ];
#define LOADM(S) \
    float a##S##0 = r0[S * 256 + tid]; \
    float a##S##1 = r1[S * 256 + tid]; \
    float a##S##2 = r2[S * 256 + tid]; \
    float a##S##3 = r3[S * 256 + tid]; \
    float a##S##4 = r4[S * 256 + tid];
    LOADM(0) LOADM(1) LOADM(2) LOADM(3)
#undef LOADM
    // pin the 20 i-point values in VGPRs (defeat remat: reloading from global
    // inside the loop was part of round-4/5's 107 cy/pair)
    asm volatile("" : "+v"(a00), "+v"(a01), "+v"(a02), "+v"(a03), "+v"(a04),
                      "+v"(a10), "+v"(a11), "+v"(a12), "+v"(a13), "+v"(a14));
    asm volatile("" : "+v"(a20), "+v"(a21), "+v"(a22), "+v"(a23), "+v"(a24),
                      "+v"(a30), "+v"(a31), "+v"(a32), "+v"(a33), "+v"(a34));

    __syncthreads();

    float acc0 = 0.f, acc1 = 0.f, acc2 = 0.f, acc3 = 0.f;
    #pragma unroll 2
    for (int jb = 0; jb < JCHUNK / 4; ++jb) {
        const float4 q0 = *reinterpret_cast<const float4*>(&mj[0][jb * 4]);
        const float4 q1 = *reinterpret_cast<const float4*>(&mj[1][jb * 4]);
        const float4 q2 = *reinterpret_cast<const float4*>(&mj[2][jb * 4]);
        const float4 q3 = *reinterpret_cast<const float4*>(&mj[3][jb * 4]);
        const float4 q4 = *reinterpret_cast<const float4*>(&mj[4][jb * 4]);
#define DOPAIR(S, C) { \
        const float d0 = a##S##0 - q0.C; \
        const float d1 = a##S##1 - q1.C; \
        const float d2 = a##S##2 - q2.C; \
        const float d3 = a##S##3 - q3.C; \
        const float d4 = a##S##4 - q4.C; \
        const float p01 = fabsf(d0) + fabsf(d1); \
        const float p23 = fabsf(d2) + fabsf(d3); \
        const float p234 = p23 + fabsf(d4); \
        const float nl = -(p01 + p234); \
        acc##S += exp2_hw(nl); }
#define DOJ(C) DOPAIR(0, C) DOPAIR(1, C) DOPAIR(2, C) DOPAIR(3, C)
        DOJ(x) DOJ(y) DOJ(z) DOJ(w)
#undef DOJ
#undef DOPAIR
    }

    atomicAdd(&out[(0 * 256 + tid) * OUTW + F_SZ + k], acc0);
    atomicAdd(&out[(1 * 256 + tid) * OUTW + F_SZ + k], acc1);
    atomicAdd(&out[(2 * 256 + tid) * OUTW + F_SZ + k], acc2);
    atomicAdd(&out[(3 * 256 + tid) * OUTW + F_SZ + k], acc3);
}

// ---------------------------------------------------------------------------
extern "C" void kernel_launch(void* const* d_in, const int* in_sizes, int n_in,
                              void* d_out, int out_size, void* d_ws, size_t ws_size,
                              hipStream_t stream) {
    const float* x = (const float*)d_in[0];   // [1024, 1024]
    const float* T = (const float*)d_in[1];   // [1024, 500]
    float* out = (float*)d_out;               // [1024, 1124]
    float* mt = (float*)d_ws;                 // [500][1024] fp32 = 2 MB (LOG2E-scaled)

    init_kernel<<<dim3(B_SZ), 320, 0, stream>>>(x, out, mt);
    gemm_mfma_splitk<<<dim3(512 / GBM, B_SZ / GBN, NSL), 256, 0, stream>>>(x, T, mt);
    pair_kernel<<<dim3(JSPLIT, NKER), 256, 0, stream>>>(mt, out);
}

// Round 7
// 135.937 us; speedup vs baseline: 2.3270x; 2.3270x over previous
//
#include <hip/hip_runtime.h>
#include <hip/hip_bf16.h>
#include <math.h>

// Problem constants
#define B_SZ   1024
#define F_SZ   1024
#define NKER   100
#define DKER   5
#define CCOLS  (NKER * DKER)   // 500
#define OUTW   (F_SZ + NKER)   // 1124
#define LOG2E_F 1.44269504088896340736f

typedef __attribute__((ext_vector_type(8))) short bf16x8;
typedef __attribute__((ext_vector_type(4))) float f32x4;

// single-instruction hardware exp2 (FTZ below 2^-126 is fine: negligible terms)
__device__ __forceinline__ float exp2_hw(float x) {
    float r;
    asm("v_exp_f32 %0, %1" : "=v"(r) : "v"(x));
    return r;
}
// pack 2 f32 -> 2 bf16 (RNE) in one instruction
__device__ __forceinline__ unsigned cvt_pk_bf16(float lo, float hi) {
    unsigned r;
    asm("v_cvt_pk_bf16_f32 %0, %1, %2" : "=v"(r) : "v"(lo), "v"(hi));
    return r;
}

// ---------------------------------------------------------------------------
// Kernel 1: copy x into out[:, :1024]. Feat region is fully written by pair
// (plain stores), mt fully written by gemm (plain stores) -> no zeroing needed.
// ---------------------------------------------------------------------------
__global__ __launch_bounds__(256) void init_kernel(const float* __restrict__ x,
                                                   float* __restrict__ out) {
    const int row = blockIdx.x;
    const int t = threadIdx.x;
    const float4 v = *reinterpret_cast<const float4*>(&x[row * F_SZ + t * 4]);
    *reinterpret_cast<float4*>(&out[row * OUTW + t * 4]) = v;
}

// ---------------------------------------------------------------------------
// Kernel 2: barrier-free wave-level bf16 MFMA GEMM (no LDS, no atomics):
//   mt[c][j] = LOG2E * sum_f x[j][f] * T[f][c]
// Each WAVE owns a 16c x 16j tile; fragments loaded straight from global
// (T, x are L2/L3-resident), packed with v_cvt_pk_bf16_f32, 32 K-steps of
// mfma_f32_16x16x32_bf16. No __syncthreads -> loads of step s+1 pipeline
// under MFMA of step s within the wave; 2048 waves = 2/SIMD, all independent.
// (Rounds 2-6 GEMMs lost to barrier serialization at 1 wave/SIMD or to
// atomic epilogues; this removes both.)
// Frag layout (verified r4-6, absmax 0.0078): A/B lane l holds 8 contiguous
// k at row/col = l&15, kchunk = (l>>4)*8; C/D col = l&15, row = (l>>4)*4+q.
// Last c-tile (c 500..511): loads clamp to c=499, stores guarded.
// ---------------------------------------------------------------------------
#define NCT 32                 // ceil(500/16) c-tiles
#define NJT (B_SZ / 16)        // 64 j-tiles

__global__ __launch_bounds__(256) void gemm_wave_kernel(const float* __restrict__ x,
                                                        const float* __restrict__ T,
                                                        float* __restrict__ mt) {
    const int tid = threadIdx.x;
    const int l = tid & 63;
    const int wv = tid >> 6;
    const int tile = blockIdx.x * 4 + wv;   // 0..2047
    const int ct = tile & (NCT - 1);
    const int jt = tile >> 5;
    const int c0 = ct * 16, j0 = jt * 16;

    const int lr = l & 15;          // frag row/col
    const int lk = (l >> 4) * 8;    // k-chunk base

    const int cA = c0 + lr;
    const int cL = (cA < CCOLS) ? cA : (CCOLS - 1);   // clamp (store-guarded)
    const int jB = j0 + lr;

    const float* ap = T + (size_t)lk * CCOLS + cL;    // A: stride CCOLS per k
    const float* bp = x + (size_t)jB * F_SZ + lk;     // B: contiguous k

    f32x4 acc = {0.f, 0.f, 0.f, 0.f};

    #pragma unroll 2
    for (int s = 0; s < F_SZ / 32; ++s) {
        // A fragment: 8 strided scalar loads (lanes 0..15 consecutive c -> 64B segs)
        const float a0 = ap[0 * CCOLS], a1 = ap[1 * CCOLS];
        const float a2 = ap[2 * CCOLS], a3 = ap[3 * CCOLS];
        const float a4 = ap[4 * CCOLS], a5 = ap[5 * CCOLS];
        const float a6 = ap[6 * CCOLS], a7 = ap[7 * CCOLS];
        // B fragment: 2 x dwordx4 along f
        const float4 b0 = *reinterpret_cast<const float4*>(bp);
        const float4 b1 = *reinterpret_cast<const float4*>(bp + 4);
        ap += 32 * CCOLS;
        bp += 32;

        union { unsigned u[4]; bf16x8 v; } A, B;
        A.u[0] = cvt_pk_bf16(a0, a1);
        A.u[1] = cvt_pk_bf16(a2, a3);
        A.u[2] = cvt_pk_bf16(a4, a5);
        A.u[3] = cvt_pk_bf16(a6, a7);
        B.u[0] = cvt_pk_bf16(b0.x, b0.y);
        B.u[1] = cvt_pk_bf16(b0.z, b0.w);
        B.u[2] = cvt_pk_bf16(b1.x, b1.y);
        B.u[3] = cvt_pk_bf16(b1.z, b1.w);

        acc = __builtin_amdgcn_mfma_f32_16x16x32_bf16(A.v, B.v, acc, 0, 0, 0);
    }

    // store (LOG2E folded): c = c0 + (l>>4)*4 + q, j = j0 + (l&15)
    const int jst = j0 + lr;
    const int cst = c0 + (l >> 4) * 4;
    #pragma unroll
    for (int q = 0; q < 4; ++q) {
        const int c = cst + q;
        if (c < CCOLS) mt[c * B_SZ + jst] = acc[q] * LOG2E_F;
    }
}

// ---------------------------------------------------------------------------
// Kernel 3: pairwise exp-L1, ZERO atomics. One thread per (i,k); full j-loop
// over 1024 in LDS chunks of 128; single plain store per thread.
// (Rounds 5/6 were atomic-bound: time tracked atomic count at ~12 G/s;
// WRITE_SIZE 102 MB in r6. Now: 102K plain stores, ~0.6 MB.)
// Grid (16, 100) = 1600 one-wave blocks = 6.25/CU (12% tail). Self term
// j==i contributes exactly exp2(0)=1. mt is pre-scaled by LOG2E.
// ---------------------------------------------------------------------------
#define PJC 128

__global__ __launch_bounds__(64) void pair_kernel(const float* __restrict__ mt,
                                                  float* __restrict__ out) {
    __shared__ float mj[DKER * PJC];
    const int tid = threadIdx.x;
    const int i = blockIdx.x * 64 + tid;
    const int k = blockIdx.y;
    const int cb = k * DKER;

    const float a0 = mt[(cb + 0) * B_SZ + i];
    const float a1 = mt[(cb + 1) * B_SZ + i];
    const float a2 = mt[(cb + 2) * B_SZ + i];
    const float a3 = mt[(cb + 3) * B_SZ + i];
    const float a4 = mt[(cb + 4) * B_SZ + i];

    float acc = 0.f;
    for (int jc = 0; jc < B_SZ; jc += PJC) {
        __syncthreads();   // single-wave: cheap; orders reuse of mj
        #pragma unroll
        for (int r = 0; r < DKER * PJC / 64; ++r) {     // 10 coalesced loads
            const int t2 = r * 64 + tid;
            const int d = t2 >> 7;          // /PJC
            const int jr = t2 & (PJC - 1);
            mj[d * PJC + jr] = mt[(cb + d) * B_SZ + jc + jr];
        }
        __syncthreads();

        #pragma unroll 4
        for (int jb = 0; jb < PJC / 4; ++jb) {
            const float4 q0 = *reinterpret_cast<const float4*>(&mj[0 * PJC + jb * 4]);
            const float4 q1 = *reinterpret_cast<const float4*>(&mj[1 * PJC + jb * 4]);
            const float4 q2 = *reinterpret_cast<const float4*>(&mj[2 * PJC + jb * 4]);
            const float4 q3 = *reinterpret_cast<const float4*>(&mj[3 * PJC + jb * 4]);
            const float4 q4 = *reinterpret_cast<const float4*>(&mj[4 * PJC + jb * 4]);
#define DOJ(C) { \
            const float d0 = a0 - q0.C; \
            const float d1 = a1 - q1.C; \
            const float d2 = a2 - q2.C; \
            const float d3 = a3 - q3.C; \
            const float d4 = a4 - q4.C; \
            const float p01 = fabsf(d0) + fabsf(d1); \
            const float p23 = fabsf(d2) + fabsf(d3); \
            const float p234 = p23 + fabsf(d4); \
            acc += exp2_hw(-p01 - p234); }
            DOJ(x) DOJ(y) DOJ(z) DOJ(w)
#undef DOJ
        }
    }

    out[i * OUTW + F_SZ + k] = acc;   // plain store, covers every (i,k)
}

// ---------------------------------------------------------------------------
extern "C" void kernel_launch(void* const* d_in, const int* in_sizes, int n_in,
                              void* d_out, int out_size, void* d_ws, size_t ws_size,
                              hipStream_t stream) {
    const float* x = (const float*)d_in[0];   // [1024, 1024]
    const float* T = (const float*)d_in[1];   // [1024, 500]
    float* out = (float*)d_out;               // [1024, 1124]
    float* mt = (float*)d_ws;                 // [500][1024] fp32, LOG2E-scaled

    init_kernel<<<dim3(B_SZ), 256, 0, stream>>>(x, out);
    gemm_wave_kernel<<<dim3(NCT * NJT / 4), 256, 0, stream>>>(x, T, mt);
    pair_kernel<<<dim3(B_SZ / 64, NKER), 64, 0, stream>>>(mt, out);
}

// Round 8
// 111.864 us; speedup vs baseline: 2.8278x; 1.2152x over previous
//
#include <hip/hip_runtime.h>
#include <hip/hip_bf16.h>
#include <math.h>

// Problem constants
#define B_SZ   1024
#define F_SZ   1024
#define NKER   100
#define DKER   5
#define CCOLS  (NKER * DKER)   // 500
#define OUTW   (F_SZ + NKER)   // 1124
#define LOG2E_F 1.44269504088896340736f

typedef __attribute__((ext_vector_type(8))) short bf16x8;
typedef __attribute__((ext_vector_type(4))) float f32x4;

// single-instruction hardware exp2 (FTZ below 2^-126 is fine: negligible terms)
__device__ __forceinline__ float exp2_hw(float x) {
    float r;
    asm("v_exp_f32 %0, %1" : "=v"(r) : "v"(x));
    return r;
}
// pack 2 f32 -> 2 bf16 (RNE) in one instruction
__device__ __forceinline__ unsigned cvt_pk_bf16(float lo, float hi) {
    unsigned r;
    asm("v_cvt_pk_bf16_f32 %0, %1, %2" : "=v"(r) : "v"(lo), "v"(hi));
    return r;
}

// ---------------------------------------------------------------------------
// Kernel 1: copy x into out[:, :1024]. Feat region fully written by pair,
// mt fully written by gemm (plain stores) -> no zeroing anywhere.
// ---------------------------------------------------------------------------
__global__ __launch_bounds__(256) void init_kernel(const float* __restrict__ x,
                                                   float* __restrict__ out) {
    const int row = blockIdx.x;
    const int t = threadIdx.x;
    const float4 v = *reinterpret_cast<const float4*>(&x[row * F_SZ + t * 4]);
    *reinterpret_cast<float4*>(&out[row * OUTW + t * 4]) = v;
}

// ---------------------------------------------------------------------------
// Kernel 2: bf16 MFMA GEMM, 32c x 32j tile, IN-BLOCK split-K (no atomics):
//   mt[c][j] = LOG2E * sum_f x[j][f] * T[f][c]
// 512 threads = 8 waves: waves 0-3 accumulate f in [0,512), waves 4-7 in
// [512,1024); each wave owns one 16x16 quadrant; LDS reduce pairs (w, w+4).
// Grid (16,32) = 512 blocks = 2 independent blocks/CU (r2-r7 GEMMs all sat
// at ~55-60us from 1-block/CU barrier serialization or scattered loads:
// r7's no-LDS B-frag loads touched 64 cache lines per instruction).
// All staging loads coalesced; frag layout as verified r4-7 (absmax 7.8e-3).
// ---------------------------------------------------------------------------
#define GAPAD 40   // LDS row: 32 bf16 + 8 pad (80 B; 8B-aligned k-offsets)

__global__ __launch_bounds__(512) void gemm_block_kernel(const float* __restrict__ x,
                                                         const float* __restrict__ T,
                                                         float* __restrict__ mt) {
    __shared__ short Al[2][32][GAPAD];   // [half][c][k] bf16
    __shared__ short Bl[2][32][GAPAD];   // [half][j][k] bf16
    __shared__ float red[4][64][4];      // cross-half reduce
    const int tid = threadIdx.x;
    const int l = tid & 63;
    const int w = tid >> 6;              // 0..7
    const int h = tid >> 8;              // K-half (== w>>2)
    const int ht = tid & 255;            // thread id within half
    const int c0 = blockIdx.x * 32;
    const int j0 = blockIdx.y * 32;
    const int fh = h * (F_SZ / 2);

    // staging maps (per half: 256 threads)
    const int sac = ht & 31;             // A: c-offset, 32 consecutive -> coalesced
    const int sak = (ht >> 5) * 4;       // A: k-base (0,4,..,28)
    const int cldA = (c0 + sac < CCOLS) ? (c0 + sac) : (CCOLS - 1);  // clamp, store-guarded
    const int sbj = ht >> 3;             // B: j-offset (0..31)
    const int sbk = (ht & 7) * 4;        // B: k-base -> float4 of contiguous f

    // fragment maps: quadrant q -> (cq, jq); lane holds 8 contig k at kchunk fr
    const int q = w & 3;
    const int cq = (q & 1) * 16;
    const int jq = (q >> 1) * 16;
    const int fr = (l >> 4) * 8;
    const int ar = cq + (l & 15);
    const int br = jq + (l & 15);

    f32x4 acc = {0.f, 0.f, 0.f, 0.f};

    for (int s = 0; s < 16; ++s) {
        const int fb = fh + s * 32;
        // issue global loads BEFORE the barrier (latency overlaps barrier wait)
        const float a0 = T[(fb + sak + 0) * CCOLS + cldA];
        const float a1 = T[(fb + sak + 1) * CCOLS + cldA];
        const float a2 = T[(fb + sak + 2) * CCOLS + cldA];
        const float a3 = T[(fb + sak + 3) * CCOLS + cldA];
        const float4 b = *reinterpret_cast<const float4*>(&x[(j0 + sbj) * F_SZ + fb + sbk]);
        if (s) __syncthreads();          // previous step's frag reads complete
        {
            uint2 aw; aw.x = cvt_pk_bf16(a0, a1); aw.y = cvt_pk_bf16(a2, a3);
            *reinterpret_cast<uint2*>(&Al[h][sac][sak]) = aw;
            uint2 bw; bw.x = cvt_pk_bf16(b.x, b.y); bw.y = cvt_pk_bf16(b.z, b.w);
            *reinterpret_cast<uint2*>(&Bl[h][sbj][sbk]) = bw;
        }
        __syncthreads();
        const bf16x8 af = *reinterpret_cast<const bf16x8*>(&Al[h][ar][fr]);
        const bf16x8 bf = *reinterpret_cast<const bf16x8*>(&Bl[h][br][fr]);
        acc = __builtin_amdgcn_mfma_f32_16x16x32_bf16(af, bf, acc, 0, 0, 0);
    }

    // cross-half reduce: wave w+4 hands its acc to wave w; wave w stores
    if (h == 1) {
        #pragma unroll
        for (int qq = 0; qq < 4; ++qq) red[q][l][qq] = acc[qq];
    }
    __syncthreads();
    if (h == 0) {
        const int jst = j0 + jq + (l & 15);
        const int cst = c0 + cq + (l >> 4) * 4;
        #pragma unroll
        for (int qq = 0; qq < 4; ++qq) {
            const int c = cst + qq;
            if (c < CCOLS)
                mt[c * B_SZ + jst] = (acc[qq] + red[q][l][qq]) * LOG2E_F;
        }
    }
}

// ---------------------------------------------------------------------------
// Kernel 3: pairwise exp-L1, no atomics. Block = 256 threads (4 waves),
// grid (16,100): stage ALL 1024 j (5 planes, 20KB LDS) once; wave w sweeps
// j-quarter w for its 64 i's; LDS reduce over waves; one store per (i,k).
// (r7: 1600x64t blocks = 1.5 waves/SIMD, Occ 12.9%, VALUBusy 52% -> latency-
// bound. Now 6400 waves = 6.25 blocks/CU.) mt is LOG2E-pre-scaled.
// ---------------------------------------------------------------------------
__global__ __launch_bounds__(256) void pair_kernel(const float* __restrict__ mt,
                                                   float* __restrict__ out) {
    __shared__ float mj[DKER][B_SZ];   // 20 KB
    __shared__ float red[256];
    const int tid = threadIdx.x;
    const int bx = blockIdx.x;          // i-chunk (64 i's)
    const int k = blockIdx.y;
    const int cb = k * DKER;

    // stage 5 x 1024 floats, coalesced float4
    #pragma unroll
    for (int d = 0; d < DKER; ++d) {
        const float4 v = *reinterpret_cast<const float4*>(&mt[(cb + d) * B_SZ + tid * 4]);
        *reinterpret_cast<float4*>(&mj[d][tid * 4]) = v;
    }
    __syncthreads();

    const int lane = tid & 63;
    const int w = tid >> 6;
    const int i = bx * 64 + lane;
    const float a0 = mj[0][i], a1 = mj[1][i], a2 = mj[2][i],
                a3 = mj[3][i], a4 = mj[4][i];

    float acc = 0.f;
    const int jbase = w * 256;          // this wave's j-quarter
    #pragma unroll 4
    for (int jb = 0; jb < 64; ++jb) {
        const int j4 = jbase + jb * 4;
        const float4 q0 = *reinterpret_cast<const float4*>(&mj[0][j4]);
        const float4 q1 = *reinterpret_cast<const float4*>(&mj[1][j4]);
        const float4 q2 = *reinterpret_cast<const float4*>(&mj[2][j4]);
        const float4 q3 = *reinterpret_cast<const float4*>(&mj[3][j4]);
        const float4 q4 = *reinterpret_cast<const float4*>(&mj[4][j4]);
#define DOJ(C) { \
        const float d0 = a0 - q0.C; \
        const float d1 = a1 - q1.C; \
        const float d2 = a2 - q2.C; \
        const float d3 = a3 - q3.C; \
        const float d4 = a4 - q4.C; \
        const float p01 = fabsf(d0) + fabsf(d1); \
        const float p23 = fabsf(d2) + fabsf(d3); \
        const float p234 = p23 + fabsf(d4); \
        acc += exp2_hw(-p01 - p234); }
        DOJ(x) DOJ(y) DOJ(z) DOJ(w)
#undef DOJ
    }

    red[tid] = acc;
    __syncthreads();
    if (tid < 64) {
        const float s = red[tid] + red[tid + 64] + red[tid + 128] + red[tid + 192];
        out[(bx * 64 + tid) * OUTW + F_SZ + k] = s;
    }
}

// ---------------------------------------------------------------------------
extern "C" void kernel_launch(void* const* d_in, const int* in_sizes, int n_in,
                              void* d_out, int out_size, void* d_ws, size_t ws_size,
                              hipStream_t stream) {
    const float* x = (const float*)d_in[0];   // [1024, 1024]
    const float* T = (const float*)d_in[1];   // [1024, 500]
    float* out = (float*)d_out;               // [1024, 1124]
    float* mt = (float*)d_ws;                 // [500][1024] fp32, LOG2E-scaled (2 MB)

    init_kernel<<<dim3(B_SZ), 256, 0, stream>>>(x, out);
    gemm_block_kernel<<<dim3(16, 32), 512, 0, stream>>>(x, T, mt);
    pair_kernel<<<dim3(B_SZ / 64, NKER), 256, 0, stream>>>(mt, out);
}